// Round 8
// baseline (333.916 us; speedup 1.0000x reference)
//
#include <hip/hip_runtime.h>
#include <math.h>

#define C_DIM 512
#define K_DIM 64
#define N_PIX 784
#define B_DIM 128
#define M_ROWS (B_DIM * N_PIX)   // 100352
#define MT 128                    // rows per block tile
#define NCH 16                    // 512 / 32 chunks

// exp(20*d - 20) = exp2(KA*d + KB)
#define KA 28.853900817779268f
#define KB (-28.853900817779268f)

typedef __attribute__((ext_vector_type(8))) short short8;            // MFMA A/B frag (8 bf16)
typedef __attribute__((ext_vector_type(4))) float f32x4;             // MFMA C/D frag
typedef __attribute__((ext_vector_type(8))) unsigned short ushort8;  // 16B

static __device__ __forceinline__ unsigned short f2bf(float f) {
    unsigned u = __builtin_bit_cast(unsigned, f);
    u += 0x7fff + ((u >> 16) & 1);  // RNE
    return (unsigned short)(u >> 16);
}
static __device__ __forceinline__ float bf2f(unsigned short h) {
    unsigned u = ((unsigned)h) << 16;
    return __builtin_bit_cast(float, u);
}
static __device__ __forceinline__ unsigned pk_bf16(float a, float b) {
    return (unsigned)f2bf(a) | ((unsigned)f2bf(b) << 16);
}

// ---------------- Kernel A: normalize anchors -> bf16 hi/lo in MFMA-frag order --------------
// Frag for (chunk ch, col-tile ct, lane L) at index ((ch*4+ct)*64 + L), holding
// B[r = ct*16 + (L&15)][k = ch*32 + (L>>4)*8 .. +7]. (layout harness-verified, baseline)
__global__ __launch_bounds__(64) void anchors_norm_kernel(const float* __restrict__ a,
                                                          ushort8* __restrict__ an_h,
                                                          ushort8* __restrict__ an_l) {
    const int k = blockIdx.x;
    const int l = threadIdx.x;  // 0..63
    const float4* ap = (const float4*)(a + (size_t)k * C_DIM);
    float4 v0 = ap[2 * l];       // cols 8l..8l+3
    float4 v1 = ap[2 * l + 1];   // cols 8l+4..8l+7
    float ss = v0.x * v0.x + v0.y * v0.y + v0.z * v0.z + v0.w * v0.w +
               v1.x * v1.x + v1.y * v1.y + v1.z * v1.z + v1.w * v1.w;
#pragma unroll
    for (int m = 1; m < 64; m <<= 1) ss += __shfl_xor(ss, m);
    const float rn = 1.0f / (sqrtf(ss) + 1e-12f);
    const float vv[8] = {v0.x * rn, v0.y * rn, v0.z * rn, v0.w * rn,
                         v1.x * rn, v1.y * rn, v1.z * rn, v1.w * rn};
    ushort8 H, L;
#pragma unroll
    for (int i = 0; i < 8; ++i) {
        const unsigned short h = f2bf(vv[i]);
        H[i] = h;
        L[i] = f2bf(vv[i] - bf2f(h));
    }
    const int idx = (((l >> 2) * 4 + (k >> 4)) * 64) + ((k & 15) | ((l & 3) << 4));
    an_h[idx] = H;
    an_l[idx] = L;
}

// One K-chunk of the cost GEMM. Issue order (with in-order vmcnt retirement):
//   pack A(c) [waits x(c), leaves B(c)+x(c+1) in flight]
//   issue B(c+1) into the OTHER parity regs (no WAR with MFMA(c))
//   MFMA(c) [waits B(c), leaves x(c+1)+x(c+2-to-be in flight]
//   issue x(c+2) into this parity's x regs (true depth-2 x pipeline)
static __device__ __forceinline__ void chunk_body(
    int c, float4& cxa0, float4& cxb0, float4& cxa1, float4& cxb1,
    ushort8 (&cbh)[4], ushort8 (&cbl)[4], ushort8 (&nbh)[4], ushort8 (&nbl)[4],
    f32x4 (&acc)[2][4], float& ss0, float& ss1,
    const float* xr0, const float* xr1,
    const ushort8* bhp, const ushort8* blp) {
    ushort8 A0, A1;
    *((unsigned*)&A0 + 0) = pk_bf16(cxa0.x, cxa0.y);
    *((unsigned*)&A0 + 1) = pk_bf16(cxa0.z, cxa0.w);
    *((unsigned*)&A0 + 2) = pk_bf16(cxb0.x, cxb0.y);
    *((unsigned*)&A0 + 3) = pk_bf16(cxb0.z, cxb0.w);
    *((unsigned*)&A1 + 0) = pk_bf16(cxa1.x, cxa1.y);
    *((unsigned*)&A1 + 1) = pk_bf16(cxa1.z, cxa1.w);
    *((unsigned*)&A1 + 2) = pk_bf16(cxb1.x, cxb1.y);
    *((unsigned*)&A1 + 3) = pk_bf16(cxb1.z, cxb1.w);
    ss0 += cxa0.x * cxa0.x + cxa0.y * cxa0.y + cxa0.z * cxa0.z + cxa0.w * cxa0.w +
           cxb0.x * cxb0.x + cxb0.y * cxb0.y + cxb0.z * cxb0.z + cxb0.w * cxb0.w;
    ss1 += cxa1.x * cxa1.x + cxa1.y * cxa1.y + cxa1.z * cxa1.z + cxa1.w * cxa1.w +
           cxb1.x * cxb1.x + cxb1.y * cxb1.y + cxb1.z * cxb1.z + cxb1.w * cxb1.w;

    // issue next chunk's B-frags early (into the other parity: no WAR with MFMAs below)
    if (c + 1 < NCH) {
        const int bb = (c + 1) * 256;
#pragma unroll
        for (int ct = 0; ct < 4; ++ct) {
            nbh[ct] = bhp[bb + ct * 64];
            nbl[ct] = blp[bb + ct * 64];
        }
    }

    const short8 a0 = __builtin_bit_cast(short8, A0);
    const short8 a1 = __builtin_bit_cast(short8, A1);
#pragma unroll
    for (int ct = 0; ct < 4; ++ct) {
        const short8 h = __builtin_bit_cast(short8, cbh[ct]);
        const short8 lo = __builtin_bit_cast(short8, cbl[ct]);
        acc[0][ct] = __builtin_amdgcn_mfma_f32_16x16x32_bf16(a0, h, acc[0][ct], 0, 0, 0);
        acc[0][ct] = __builtin_amdgcn_mfma_f32_16x16x32_bf16(a0, lo, acc[0][ct], 0, 0, 0);
        acc[1][ct] = __builtin_amdgcn_mfma_f32_16x16x32_bf16(a1, h, acc[1][ct], 0, 0, 0);
        acc[1][ct] = __builtin_amdgcn_mfma_f32_16x16x32_bf16(a1, lo, acc[1][ct], 0, 0, 0);
    }

    // issue x(c+2) into this parity's registers (pack above already consumed them)
    if (c + 2 < NCH) {
        const int c0 = (c + 2) * 32;
        cxa0 = *(const float4*)(xr0 + c0);
        cxb0 = *(const float4*)(xr0 + c0 + 4);
        cxa1 = *(const float4*)(xr1 + c0);
        cxb1 = *(const float4*)(xr1 + c0 + 4);
    }
}

// ---------------- Kernel B: cosine GEMM via MFMA + T — barrier-free, depth-2 pipeline ------
// 784 blocks x 256 threads (4 waves). Block tile 128 rows x 64 anchors; wave w owns
// rows w*32..+31. R5/R6 evidence: latency-bound (all pipes <10%), so this version
// doubles in-flight HBM bytes (2-chunk x prefetch, parity regs) and removes the
// 64 v_mov/chunk operand copies. Math sequence bit-identical to R6.
__global__ __launch_bounds__(256, 3) void cost_t_kernel(const float* __restrict__ x,
                                                        const ushort8* __restrict__ an_h,
                                                        const ushort8* __restrict__ an_l,
                                                        float* __restrict__ Tg) {
    __shared__ float nrm[MT];

    const int tid = threadIdx.x;
    const int m0 = blockIdx.x * MT;
    const int w = tid >> 6;   // wave 0..3
    const int l = tid & 63;   // lane
    const int fr = l & 15;
    const int ko = (l >> 4) * 8;  // k offset within chunk (floats)

    const float* xr0 = x + (size_t)(m0 + w * 32 + fr) * C_DIM + ko;
    const float* xr1 = xr0 + 16 * C_DIM;
    const ushort8* bhp = an_h + l;
    const ushort8* blp = an_l + l;

    f32x4 acc[2][4];
#pragma unroll
    for (int rt = 0; rt < 2; ++rt)
#pragma unroll
        for (int ct = 0; ct < 4; ++ct) acc[rt][ct] = (f32x4){0.f, 0.f, 0.f, 0.f};
    float ss0 = 0.f, ss1 = 0.f;

    // prologue issue order: x(0), B(0), x(1)  (keeps B(0) older than x(1) so the
    // MFMA(0) wait doesn't force x(1) retirement)
    float4 xa00 = *(const float4*)(xr0);
    float4 xb00 = *(const float4*)(xr0 + 4);
    float4 xa10 = *(const float4*)(xr1);
    float4 xb10 = *(const float4*)(xr1 + 4);
    ushort8 bh0[4], bl0[4], bh1[4], bl1[4];
#pragma unroll
    for (int ct = 0; ct < 4; ++ct) { bh0[ct] = bhp[ct * 64]; bl0[ct] = blp[ct * 64]; }
    float4 xa01 = *(const float4*)(xr0 + 32);
    float4 xb01 = *(const float4*)(xr0 + 36);
    float4 xa11 = *(const float4*)(xr1 + 32);
    float4 xb11 = *(const float4*)(xr1 + 36);

#pragma unroll 1
    for (int c = 0; c < NCH; c += 2) {
        chunk_body(c,     xa00, xb00, xa10, xb10, bh0, bl0, bh1, bl1,
                   acc, ss0, ss1, xr0, xr1, bhp, blp);
        chunk_body(c + 1, xa01, xb01, xa11, xb11, bh1, bl1, bh0, bl0,
                   acc, ss0, ss1, xr0, xr1, bhp, blp);
    }

    // full-row sumsq: lanes {l, l+16, l+32, l+48} hold complementary k-slices
    ss0 += __shfl_xor(ss0, 16); ss0 += __shfl_xor(ss0, 32);
    ss1 += __shfl_xor(ss1, 16); ss1 += __shfl_xor(ss1, 32);
    if (l < 16) {
        nrm[w * 32 + fr] = 1.0f / (sqrtf(ss0) + 1e-12f);
        nrm[w * 32 + 16 + fr] = 1.0f / (sqrtf(ss1) + 1e-12f);
    }
    __syncthreads();

    // epilogue: C/D layout col=l&15, row=(l>>4)*4+i ; T[m] = sum_k exp(20*cos - 20)
#pragma unroll
    for (int rt = 0; rt < 2; ++rt) {
#pragma unroll
        for (int i = 0; i < 4; ++i) {
            const int m = w * 32 + rt * 16 + ((l >> 4) << 2) + i;
            const float rn = nrm[m];
            float t = exp2f(KA * (acc[rt][0][i] * rn) + KB) +
                      exp2f(KA * (acc[rt][1][i] * rn) + KB) +
                      exp2f(KA * (acc[rt][2][i] * rn) + KB) +
                      exp2f(KA * (acc[rt][3][i] * rn) + KB);
            t += __shfl_xor(t, 1); t += __shfl_xor(t, 2);
            t += __shfl_xor(t, 4); t += __shfl_xor(t, 8);
            if ((l & 15) == 0) Tg[m0 + m] = t;
        }
    }
}

// ---------------- Kernel C: sinkhorn + weighted pooling, 8-way split (R6 verbatim) --------
__global__ __launch_bounds__(256) void pool_partial(const float* __restrict__ x,
                                                    const float* __restrict__ Tg,
                                                    float* __restrict__ part) {
    const int bid = blockIdx.x;
    const int b = bid >> 3;
    const int o = bid & 7;
    const int tid = threadIdx.x;
    __shared__ float wsum[4];
    __shared__ float wsh;
    __shared__ float cf[98];
    __shared__ float prt[2][C_DIM];

    float r[4];
#pragma unroll
    for (int qq = 0; qq < 4; ++qq) {
        const int n = tid + qq * 256;
        r[qq] = (n < N_PIX) ? Tg[b * N_PIX + n] : 0.f;
    }
    float wv = 1.0f;
    for (int it = 0; it < 10; ++it) {
        float p = 0.f;
#pragma unroll
        for (int qq = 0; qq < 4; ++qq) {
            const float wr = wv * r[qq];
            p += wr / (1.0f + wr);
        }
#pragma unroll
        for (int m = 1; m < 64; m <<= 1) p += __shfl_xor(p, m);
        if ((tid & 63) == 0) wsum[tid >> 6] = p;
        __syncthreads();
        if (tid == 0) {
            const float s = wsum[0] + wsum[1] + wsum[2] + wsum[3];
            wsh = wv * 392.0f / s;  // mu*N = 0.5*784
        }
        __syncthreads();
        wv = wsh;
    }
    if (tid < 98) {
        const float wr = wv * Tg[b * N_PIX + o * 98 + tid];
        cf[tid] = (2.0f / 784.0f) * wr / (1.0f + wr);
    }
    __syncthreads();

    const int half = tid >> 7;
    const int c4 = (tid & 127) * 4;
    const float* xb = x + ((size_t)b * N_PIX + o * 98) * C_DIM + c4;
    float4 acc = {0.f, 0.f, 0.f, 0.f};
#pragma unroll 7
    for (int i = 0; i < 49; ++i) {
        const int n = 2 * i + half;
        const float a = cf[n];  // wave-uniform LDS broadcast
        const float4 xv = *(const float4*)(xb + (size_t)n * C_DIM);
        acc.x += a * xv.x; acc.y += a * xv.y; acc.z += a * xv.z; acc.w += a * xv.w;
    }
    *(float4*)(&prt[half][c4]) = acc;
    __syncthreads();
    if (tid < 128) {
        const int c = tid * 4;
        const float4 e = *(const float4*)(&prt[0][c]);
        const float4 od = *(const float4*)(&prt[1][c]);
        float4 s;
        s.x = e.x + od.x; s.y = e.y + od.y; s.z = e.z + od.z; s.w = e.w + od.w;
        *(float4*)(part + (size_t)bid * C_DIM + c) = s;
    }
}

__global__ __launch_bounds__(256) void pool_reduce(const float* __restrict__ part,
                                                   float* __restrict__ out) {
    const int i = blockIdx.x * 256 + threadIdx.x;  // over b*512 + c
    const int b = i >> 9;
    const int c = i & 511;
    const float* p = part + (size_t)b * 8 * C_DIM + c;
    float s = 0.f;
#pragma unroll
    for (int j = 0; j < 8; ++j) s += p[j * C_DIM];
    out[i] = s;
}

extern "C" void kernel_launch(void* const* d_in, const int* in_sizes, int n_in,
                              void* d_out, int out_size, void* d_ws, size_t ws_size,
                              hipStream_t stream) {
    const float* x = (const float*)d_in[0];       // (128,28,28,512) fp32
    const float* anchors = (const float*)d_in[1]; // (64,512) fp32
    float* out = (float*)d_out;                   // (128,512) fp32

    ushort8* an_h = (ushort8*)d_ws;                       // 4096 frags (64 KB)
    ushort8* an_l = an_h + 4096;                          // 64 KB
    float* Tg = (float*)(an_l + 4096);                    // 128*784 fp32
    float* part = Tg + (size_t)B_DIM * N_PIX;             // 1024*512 fp32 (2 MB)

    anchors_norm_kernel<<<K_DIM, 64, 0, stream>>>(anchors, an_h, an_l);
    cost_t_kernel<<<M_ROWS / MT, 256, 0, stream>>>(x, an_h, an_l, Tg);
    pool_partial<<<B_DIM * 8, 256, 0, stream>>>(x, Tg, part);
    pool_reduce<<<B_DIM * C_DIM / 256, 256, 0, stream>>>(part, out);
}